// Round 11
// baseline (106.666 us; speedup 1.0000x reference)
//
#include <hip/hip_runtime.h>
#include <hip/hip_bf16.h>

#define NB 64
#define NU 64
#define NT 512
#define NH 8
#define KNN 9
#define PAD 9
#define UPB 8
#define NEGV -1000000000.0f

// fast tanh via hardware exp: exact at saturation
__device__ __forceinline__ float ft(float x) {
    return 1.f - 2.f / (__expf(2.f * x) + 1.f);
}

// =====================================================================
// Kernel A (k_usv2): grid = NB*8 blocks; block = (b, 8 u's), 512 thr.
// Stage te (LDS) + own-task tk (registers) once; loop 8 u's with
// wave-local max softmax + cross-wave online merge (1 barrier per u,
// double-buffered by parity). Thread t owns task t throughout.
// =====================================================================
__global__ void __launch_bounds__(512) k_usv2(
    const float* __restrict__ usv_f, const float* __restrict__ task_f,
    const int* __restrict__ adj,
    const float* __restrict__ W_usv, const float* __restrict__ b_usv,
    const float* __restrict__ W_task, const float* __restrict__ b_task,
    const float* __restrict__ W_au, const float* __restrict__ b_au,
    const float* __restrict__ W_Q, const float* __restrict__ b_Q,
    const float* __restrict__ W_K, const float* __restrict__ b_K,
    float* __restrict__ out_usv)
{
    __shared__ float s_te[NT][PAD];
    __shared__ float s_p[NT];
    __shared__ float s_q[UPB][PAD];
    __shared__ float s_ue[UPB][PAD];
    __shared__ float s_mw[2][8];
    __shared__ float s_sw[2][8];
    __shared__ float s_wp[2][8][NH];

    const int b    = blockIdx.x >> 3;
    const int u0   = (blockIdx.x & 7) * UPB;
    const int t    = threadIdx.x;
    const int lane = t & 63, wv = t >> 6;

    // --- staging: thread t -> te[t] (LDS) + tk[t] (regs) ---
    float tkr[NH];
    {
        float f[5];
        #pragma unroll
        for (int j = 0; j < 5; ++j) f[j] = task_f[(b * NT + t) * 5 + j];
        float e[NH];
        #pragma unroll
        for (int h = 0; h < NH; ++h) {
            float a = b_task[h];
            #pragma unroll
            for (int j = 0; j < 5; ++j) a += f[j] * W_task[j * NH + h];
            e[h] = a;
            s_te[t][h] = a;
        }
        #pragma unroll
        for (int h = 0; h < NH; ++h) {
            float a = b_K[h];
            #pragma unroll
            for (int j = 0; j < NH; ++j) a += e[j] * W_K[j * NH + h];
            tkr[h] = a;
        }
    }
    // --- u staging: threads 0..UPB-1 -> ue, q into LDS ---
    if (t < UPB) {
        int u = u0 + t;
        float f0 = usv_f[(b * NU + u) * 4 + 0];
        float f1 = usv_f[(b * NU + u) * 4 + 1];
        float f2 = usv_f[(b * NU + u) * 4 + 2];
        float f3 = usv_f[(b * NU + u) * 4 + 3];
        float ue[NH];
        #pragma unroll
        for (int h = 0; h < NH; ++h) {
            ue[h] = b_usv[h] + f0 * W_usv[0 * NH + h] + f1 * W_usv[1 * NH + h]
                             + f2 * W_usv[2 * NH + h] + f3 * W_usv[3 * NH + h];
            s_ue[t][h] = ue[h];
        }
        #pragma unroll
        for (int h = 0; h < NH; ++h) {
            float a = b_Q[h];
            #pragma unroll
            for (int j = 0; j < NH; ++j) a += ue[j] * W_Q[j * NH + h];
            s_q[t][h] = a;
        }
    }
    float wau[NH];
    #pragma unroll
    for (int h = 0; h < NH; ++h) wau[h] = W_au[h];
    float bau = b_au[0];
    __syncthreads();

    for (int ui = 0; ui < UPB; ++ui) {
        const int par = ui & 1;
        const int u = u0 + ui;

        float sc = bau;
        #pragma unroll
        for (int h = 0; h < NH; ++h) sc += ft(s_q[ui][h] + tkr[h]) * wau[h];
        if (adj[(b * NU + u) * NT + t] == 0) sc = NEGV;

        // wave-local max (no cross-wave barrier needed)
        float m = sc;
        #pragma unroll
        for (int o = 32; o; o >>= 1) m = fmaxf(m, __shfl_xor(m, o));
        float p = __expf(sc - m);
        s_p[t] = p;
        float ps = p;
        #pragma unroll
        for (int o = 32; o; o >>= 1) ps += __shfl_xor(ps, o);
        if (lane == 0) { s_mw[par][wv] = m; s_sw[par][wv] = ps; }

        // (g,h) partial agg over this wave's 64 tasks (same-wave LDS)
        const int g8 = t & ~7, hh = t & 7;
        float part = 0.f;
        #pragma unroll
        for (int i = 0; i < 8; ++i)
            part += s_p[g8 + i] * s_te[g8 + i][hh];
        part += __shfl_xor(part, 8);
        part += __shfl_xor(part, 16);
        part += __shfl_xor(part, 32);
        if (lane < NH) s_wp[par][wv][lane] = part;
        __syncthreads();

        // final: threads 0-7 merge 8 waves with online rescale
        if (t < NH) {
            float M = s_mw[par][0];
            #pragma unroll
            for (int w = 1; w < 8; ++w) M = fmaxf(M, s_mw[par][w]);
            float PS = 0.f, A = 0.f;
            #pragma unroll
            for (int w = 0; w < 8; ++w) {
                float ew = __expf(s_mw[par][w] - M);
                PS += s_sw[par][w] * ew;
                A  += s_wp[par][w][t] * ew;
            }
            float qh = s_q[ui][t], ueh = s_ue[ui][t];
            float sig = 1.f / (1.f + __expf(-qh));
            float x = sig * ueh + A / PS;
            float upd = x > 0.f ? x : __expf(x) - 1.f;
            out_usv[(b * NU + u) * NH + t] = upd;
        }
    }
}

// =====================================================================
// Kernel B (k_task5): grid = NB*16 blocks; block stages once, then
// loops 4 task-groups (8 tasks each, wave-per-task). kNN u64-key
// extraction identical to round 10. tq computed on 8 lanes -> s_tq.
// No barriers inside the k-loop (all exchanges wave-local).
// =====================================================================
__global__ void __launch_bounds__(512) k_task5(
    const float* __restrict__ task_f,
    const float* __restrict__ W_task, const float* __restrict__ b_task,
    const float* __restrict__ W_K, const float* __restrict__ b_K,
    const float* __restrict__ W_V, const float* __restrict__ b_V,
    const float* __restrict__ W_Q, const float* __restrict__ b_Q,
    const float* __restrict__ W_at, const float* __restrict__ b_at,
    const float* __restrict__ out_usv,
    float* __restrict__ out_task)
{
    __shared__ float s_cx[NT], s_cy[NT];
    __shared__ float s_te[NT][PAD];
    __shared__ float s_tk[NT][PAD];
    __shared__ float s_up[NU][PAD];
    __shared__ float s_uk[NU][PAD];
    __shared__ float s_p2[8][12];
    __shared__ int   s_nb[8][12];
    __shared__ float s_pu[8][NU];
    __shared__ float s_tq[8][PAD];

    const int b     = blockIdx.x >> 4;
    const int tile0 = blockIdx.x & 15;
    const int wid   = threadIdx.x >> 6;
    const int lane  = threadIdx.x & 63;

    // --- staging: thread i computes te/tk/coords for task i ---
    {
        int i = threadIdx.x;
        float f[5];
        #pragma unroll
        for (int j = 0; j < 5; ++j) f[j] = task_f[(b * NT + i) * 5 + j];
        s_cx[i] = f[0]; s_cy[i] = f[1];
        float e[NH];
        #pragma unroll
        for (int h = 0; h < NH; ++h) {
            float a = b_task[h];
            #pragma unroll
            for (int j = 0; j < 5; ++j) a += f[j] * W_task[j * NH + h];
            e[h] = a;
            s_te[i][h] = a;
        }
        #pragma unroll
        for (int h = 0; h < NH; ++h) {
            float a = b_K[h];
            #pragma unroll
            for (int j = 0; j < NH; ++j) a += e[j] * W_K[j * NH + h];
            s_tk[i][h] = a;
        }
    }
    if (threadIdx.x < NU) {
        int u = threadIdx.x;
        float up[NH];
        #pragma unroll
        for (int h = 0; h < NH; ++h) {
            up[h] = out_usv[(b * NU + u) * NH + h];
            s_up[u][h] = up[h];
        }
        #pragma unroll
        for (int h = 0; h < NH; ++h) {
            float a = b_Q[h];
            #pragma unroll
            for (int j = 0; j < NH; ++j) a += up[j] * W_Q[j * NH + h];
            s_uk[u][h] = a;
        }
    }
    __syncthreads();

    float wat[NH];
    #pragma unroll
    for (int h = 0; h < NH; ++h) wat[h] = W_at[h];
    const float bat = b_at[0];

    for (int k = 0; k < 4; ++k) {
        const int tile = (tile0 << 2) | k;
        const int t    = tile * 8 + wid;

        // --- phase 1: u64-key kNN, 9-round lex-min extraction ---
        float mx = s_cx[t], my = s_cy[t];
        unsigned long long kl[8];
        #pragma unroll
        for (int i = 0; i < 8; ++i) {
            int s = i * 64 + lane;
            float dx = mx - s_cx[s], dy = my - s_cy[s];
            float d = sqrtf(dx * dx + dy * dy);
            kl[i] = ((unsigned long long)__float_as_uint(d) << 32) | (unsigned)s;
        }
        int mynb = t;
        #pragma unroll
        for (int j = 0; j < KNN; ++j) {
            unsigned long long bk = kl[0];
            #pragma unroll
            for (int i = 1; i < 8; ++i) bk = (kl[i] < bk) ? kl[i] : bk;
            #pragma unroll
            for (int o = 32; o; o >>= 1) {
                unsigned long long k2 = __shfl_xor(bk, o);
                bk = (k2 < bk) ? k2 : bk;
            }
            if (lane == j) mynb = (int)(bk & 511ULL);
            unsigned sw = (unsigned)bk;
            if ((sw & 63u) == (unsigned)lane) {
                int slot = (int)(sw >> 6) & 7;
                #pragma unroll
                for (int i = 0; i < 8; ++i) if (i == slot) kl[i] = ~0ULL;
            }
        }

        // --- tq on lanes 0-7 -> s_tq (wave-local) ---
        if (lane < NH) {
            float a = b_V[lane];
            #pragma unroll
            for (int j = 0; j < NH; ++j) a += s_te[t][j] * W_V[j * NH + lane];
            s_tq[wid][lane] = a;
        }

        // --- phase 2: neighbor scoring (lanes 0-8 meaningful) ---
        float sc2 = bat;
        #pragma unroll
        for (int h = 0; h < NH; ++h)
            sc2 += ft(s_tq[wid][h] + s_tk[mynb][h]) * wat[h];
        float a2 = (lane < KNN) ? sc2 : -3.0e38f;
        float vm = a2;
        #pragma unroll
        for (int o = 8; o; o >>= 1) vm = fmaxf(vm, __shfl_xor(vm, o));
        float p2 = (lane < KNN) ? __expf(a2 - vm) : 0.f;
        float ss = p2;
        #pragma unroll
        for (int o = 8; o; o >>= 1) ss += __shfl_xor(ss, o);
        if (lane < KNN) { s_p2[wid][lane] = p2; s_nb[wid][lane] = mynb; }
        float aT = 0.f;
        if (lane < NH) {
            #pragma unroll
            for (int j2 = 0; j2 < KNN; ++j2)
                aT += s_p2[wid][j2] * s_te[s_nb[wid][j2]][lane];
        }

        // --- phase 3: u-softmax, lane = u; (g,h) aggU ---
        float au = bat;
        #pragma unroll
        for (int h = 0; h < NH; ++h)
            au += ft(s_uk[lane][h] + s_tq[wid][h]) * wat[h];
        float um = au;
        #pragma unroll
        for (int o = 32; o; o >>= 1) um = fmaxf(um, __shfl_xor(um, o));
        float pu = __expf(au - um);
        float su = pu;
        #pragma unroll
        for (int o = 32; o; o >>= 1) su += __shfl_xor(su, o);
        s_pu[wid][lane] = pu;
        const int gb = (lane >> 3) << 3;
        const int hh = lane & 7;
        float aU = 0.f;
        #pragma unroll
        for (int i = 0; i < 8; ++i)
            aU += s_pu[wid][gb + i] * s_up[gb + i][hh];
        aU += __shfl_xor(aU, 8);
        aU += __shfl_xor(aU, 16);
        aU += __shfl_xor(aU, 32);

        // --- finalize on lanes 0-7 (h = lane) ---
        if (lane < NH) {
            float tqh = s_tq[wid][lane];
            float invT = 1.f / ss, invU = 1.f / su;
            float sig = 1.f / (1.f + __expf(-tqh));
            float x = sig * s_te[t][lane] + aT * invT + aU * invU;
            float r = x > 0.f ? x : __expf(x) - 1.f;
            out_task[(b * NT + t) * NH + lane] = r;
        }
    }
}

extern "C" void kernel_launch(void* const* d_in, const int* in_sizes, int n_in,
                              void* d_out, int out_size, void* d_ws, size_t ws_size,
                              hipStream_t stream)
{
    const float* usv_f  = (const float*)d_in[0];
    const float* task_f = (const float*)d_in[1];
    const int*   adj    = (const int*)  d_in[2];
    // d_in[3] edge_features: unused by the reference
    const float* W_usv  = (const float*)d_in[4];
    const float* b_usv  = (const float*)d_in[5];
    const float* W_task = (const float*)d_in[6];
    const float* b_task = (const float*)d_in[7];
    const float* W_au   = (const float*)d_in[8];
    const float* b_au   = (const float*)d_in[9];
    const float* W_at   = (const float*)d_in[10];
    const float* b_at   = (const float*)d_in[11];
    const float* W_Q    = (const float*)d_in[12];
    const float* b_Q    = (const float*)d_in[13];
    const float* W_K    = (const float*)d_in[14];
    const float* b_K    = (const float*)d_in[15];
    const float* W_V    = (const float*)d_in[16];
    const float* b_V    = (const float*)d_in[17];

    float* out_usv  = (float*)d_out;
    float* out_task = out_usv + NB * NU * NH;

    hipLaunchKernelGGL(k_usv2, dim3(NB * 8), dim3(512), 0, stream,
                       usv_f, task_f, adj,
                       W_usv, b_usv, W_task, b_task, W_au, b_au,
                       W_Q, b_Q, W_K, b_K, out_usv);
    hipLaunchKernelGGL(k_task5, dim3(NB * 16), dim3(512), 0, stream,
                       task_f, W_task, b_task, W_K, b_K, W_V, b_V,
                       W_Q, b_Q, W_at, b_at, out_usv, out_task);
}

// Round 12
// 83.891 us; speedup vs baseline: 1.2715x; 1.2715x over previous
//
#include <hip/hip_runtime.h>
#include <hip/hip_bf16.h>

#define NB 64
#define NU 64
#define NT 512
#define NH 8
#define KNN 9
#define PAD 9
#define UPB 8
#define NEGV -1000000000.0f

typedef unsigned long long ull;

// fast tanh via hardware exp: exact at saturation
__device__ __forceinline__ float ft(float x) {
    return 1.f - 2.f / (__expf(2.f * x) + 1.f);
}

// =====================================================================
// Kernel A (k_usv2): unchanged from round 11 (passing, 14.3us).
// =====================================================================
__global__ void __launch_bounds__(512) k_usv2(
    const float* __restrict__ usv_f, const float* __restrict__ task_f,
    const int* __restrict__ adj,
    const float* __restrict__ W_usv, const float* __restrict__ b_usv,
    const float* __restrict__ W_task, const float* __restrict__ b_task,
    const float* __restrict__ W_au, const float* __restrict__ b_au,
    const float* __restrict__ W_Q, const float* __restrict__ b_Q,
    const float* __restrict__ W_K, const float* __restrict__ b_K,
    float* __restrict__ out_usv)
{
    __shared__ float s_te[NT][PAD];
    __shared__ float s_p[NT];
    __shared__ float s_q[UPB][PAD];
    __shared__ float s_ue[UPB][PAD];
    __shared__ float s_mw[2][8];
    __shared__ float s_sw[2][8];
    __shared__ float s_wp[2][8][NH];

    const int b    = blockIdx.x >> 3;
    const int u0   = (blockIdx.x & 7) * UPB;
    const int t    = threadIdx.x;
    const int lane = t & 63, wv = t >> 6;

    float tkr[NH];
    {
        float f[5];
        #pragma unroll
        for (int j = 0; j < 5; ++j) f[j] = task_f[(b * NT + t) * 5 + j];
        float e[NH];
        #pragma unroll
        for (int h = 0; h < NH; ++h) {
            float a = b_task[h];
            #pragma unroll
            for (int j = 0; j < 5; ++j) a += f[j] * W_task[j * NH + h];
            e[h] = a;
            s_te[t][h] = a;
        }
        #pragma unroll
        for (int h = 0; h < NH; ++h) {
            float a = b_K[h];
            #pragma unroll
            for (int j = 0; j < NH; ++j) a += e[j] * W_K[j * NH + h];
            tkr[h] = a;
        }
    }
    if (t < UPB) {
        int u = u0 + t;
        float f0 = usv_f[(b * NU + u) * 4 + 0];
        float f1 = usv_f[(b * NU + u) * 4 + 1];
        float f2 = usv_f[(b * NU + u) * 4 + 2];
        float f3 = usv_f[(b * NU + u) * 4 + 3];
        float ue[NH];
        #pragma unroll
        for (int h = 0; h < NH; ++h) {
            ue[h] = b_usv[h] + f0 * W_usv[0 * NH + h] + f1 * W_usv[1 * NH + h]
                             + f2 * W_usv[2 * NH + h] + f3 * W_usv[3 * NH + h];
            s_ue[t][h] = ue[h];
        }
        #pragma unroll
        for (int h = 0; h < NH; ++h) {
            float a = b_Q[h];
            #pragma unroll
            for (int j = 0; j < NH; ++j) a += ue[j] * W_Q[j * NH + h];
            s_q[t][h] = a;
        }
    }
    float wau[NH];
    #pragma unroll
    for (int h = 0; h < NH; ++h) wau[h] = W_au[h];
    float bau = b_au[0];
    __syncthreads();

    for (int ui = 0; ui < UPB; ++ui) {
        const int par = ui & 1;
        const int u = u0 + ui;

        float sc = bau;
        #pragma unroll
        for (int h = 0; h < NH; ++h) sc += ft(s_q[ui][h] + tkr[h]) * wau[h];
        if (adj[(b * NU + u) * NT + t] == 0) sc = NEGV;

        float m = sc;
        #pragma unroll
        for (int o = 32; o; o >>= 1) m = fmaxf(m, __shfl_xor(m, o));
        float p = __expf(sc - m);
        s_p[t] = p;
        float ps = p;
        #pragma unroll
        for (int o = 32; o; o >>= 1) ps += __shfl_xor(ps, o);
        if (lane == 0) { s_mw[par][wv] = m; s_sw[par][wv] = ps; }

        const int g8 = t & ~7, hh = t & 7;
        float part = 0.f;
        #pragma unroll
        for (int i = 0; i < 8; ++i)
            part += s_p[g8 + i] * s_te[g8 + i][hh];
        part += __shfl_xor(part, 8);
        part += __shfl_xor(part, 16);
        part += __shfl_xor(part, 32);
        if (lane < NH) s_wp[par][wv][lane] = part;
        __syncthreads();

        if (t < NH) {
            float M = s_mw[par][0];
            #pragma unroll
            for (int w = 1; w < 8; ++w) M = fmaxf(M, s_mw[par][w]);
            float PS = 0.f, A = 0.f;
            #pragma unroll
            for (int w = 0; w < 8; ++w) {
                float ew = __expf(s_mw[par][w] - M);
                PS += s_sw[par][w] * ew;
                A  += s_wp[par][w][t] * ew;
            }
            float qh = s_q[ui][t], ueh = s_ue[ui][t];
            float sig = 1.f / (1.f + __expf(-qh));
            float x = sig * ueh + A / PS;
            float upd = x > 0.f ? x : __expf(x) - 1.f;
            out_usv[(b * NU + u) * NH + t] = upd;
        }
    }
}

// =====================================================================
// Kernel B (k_task6): grid = NB*8 blocks (block = 64 tasks), 512 thr.
// kNN: 8-lane groups, per-lane sorted top-9 (u64 lex keys) over 64
// candidates + 9-round group-butterfly merge -> s_nbi. Phases 2/3:
// verified round-10 per-wave code looped over the wave's 8 tasks.
// =====================================================================
__global__ void __launch_bounds__(512) k_task6(
    const float* __restrict__ task_f,
    const float* __restrict__ W_task, const float* __restrict__ b_task,
    const float* __restrict__ W_K, const float* __restrict__ b_K,
    const float* __restrict__ W_V, const float* __restrict__ b_V,
    const float* __restrict__ W_Q, const float* __restrict__ b_Q,
    const float* __restrict__ W_at, const float* __restrict__ b_at,
    const float* __restrict__ out_usv,
    float* __restrict__ out_task)
{
    __shared__ float2 s_cxy[NT];
    __shared__ float s_te[NT][PAD];
    __shared__ float s_tk[NT][PAD];
    __shared__ float s_up[NU][PAD];
    __shared__ float s_uk[NU][PAD];
    __shared__ int   s_nbi[8][8][KNN];   // [wave][group][rank]
    __shared__ float s_p2[8][12];
    __shared__ float s_pu[8][NU];
    __shared__ float s_tq[8][PAD];

    const int b     = blockIdx.x >> 3;
    const int tile  = blockIdx.x & 7;
    const int wid   = threadIdx.x >> 6;
    const int lane  = threadIdx.x & 63;
    const int grp   = lane >> 3;          // group within wave
    const int lig   = lane & 7;           // lane in group
    const int tbase = tile * 64;
    const int myTask = tbase + wid * 8 + grp;   // kNN task of this lane

    // --- staging: thread i -> te/tk/coords of task i ---
    {
        int i = threadIdx.x;
        float f[5];
        #pragma unroll
        for (int j = 0; j < 5; ++j) f[j] = task_f[(b * NT + i) * 5 + j];
        s_cxy[i] = make_float2(f[0], f[1]);
        float e[NH];
        #pragma unroll
        for (int h = 0; h < NH; ++h) {
            float a = b_task[h];
            #pragma unroll
            for (int j = 0; j < 5; ++j) a += f[j] * W_task[j * NH + h];
            e[h] = a;
            s_te[i][h] = a;
        }
        #pragma unroll
        for (int h = 0; h < NH; ++h) {
            float a = b_K[h];
            #pragma unroll
            for (int j = 0; j < NH; ++j) a += e[j] * W_K[j * NH + h];
            s_tk[i][h] = a;
        }
    }
    if (threadIdx.x < NU) {
        int u = threadIdx.x;
        float up[NH];
        #pragma unroll
        for (int h = 0; h < NH; ++h) {
            up[h] = out_usv[(b * NU + u) * NH + h];
            s_up[u][h] = up[h];
        }
        #pragma unroll
        for (int h = 0; h < NH; ++h) {
            float a = b_Q[h];
            #pragma unroll
            for (int j = 0; j < NH; ++j) a += up[j] * W_Q[j * NH + h];
            s_uk[u][h] = a;
        }
    }
    __syncthreads();

    // --- kNN: per-lane sorted top-9 over candidates s = i*8+lig ---
    {
        float mx = s_cxy[myTask].x, my = s_cxy[myTask].y;
        ull a[KNN];
        #pragma unroll
        for (int j = 0; j < KNN; ++j) a[j] = ~0ULL;
        for (int i = 0; i < 64; ++i) {
            int s = i * 8 + lig;
            float2 c = s_cxy[s];
            float dx = mx - c.x, dy = my - c.y;
            float d = sqrtf(dx * dx + dy * dy);
            ull k = ((ull)__float_as_uint(d) << 32) | (unsigned)s;
            bool cnd[KNN];
            #pragma unroll
            for (int j = 0; j < KNN; ++j) cnd[j] = k < a[j];
            #pragma unroll
            for (int j = KNN - 1; j >= 1; --j)
                a[j] = cnd[j] ? (cnd[j - 1] ? a[j - 1] : k) : a[j];
            a[0] = cnd[0] ? k : a[0];
        }
        // merge within 8-lane group: 9 extraction rounds
        #pragma unroll
        for (int r = 0; r < KNN; ++r) {
            ull m = a[0];
            #pragma unroll
            for (int o = 1; o <= 4; o <<= 1) {
                ull m2 = __shfl_xor(m, o);
                m = (m2 < m) ? m2 : m;
            }
            if (lig == 0) s_nbi[wid][grp][r] = (int)(m & 511ULL);
            bool won = (a[0] == m);
            #pragma unroll
            for (int j = 0; j < KNN - 1; ++j) a[j] = won ? a[j + 1] : a[j];
            a[KNN - 1] = won ? ~0ULL : a[KNN - 1];
        }
    }

    float wat[NH];
    #pragma unroll
    for (int h = 0; h < NH; ++h) wat[h] = W_at[h];
    const float bat = b_at[0];

    // --- phases 2+3 (verified round-10 code), looped over 8 tasks ---
    for (int g = 0; g < 8; ++g) {
        const int t = tbase + wid * 8 + g;
        const int mynb = (lane < KNN) ? s_nbi[wid][g][lane] : t;

        // tq on lanes 0-7 -> s_tq (wave-local)
        if (lane < NH) {
            float a = b_V[lane];
            #pragma unroll
            for (int j = 0; j < NH; ++j) a += s_te[t][j] * W_V[j * NH + lane];
            s_tq[wid][lane] = a;
        }

        // phase 2: neighbor scoring (lanes 0-8 meaningful)
        float sc2 = bat;
        #pragma unroll
        for (int h = 0; h < NH; ++h)
            sc2 += ft(s_tq[wid][h] + s_tk[mynb][h]) * wat[h];
        float a2 = (lane < KNN) ? sc2 : -3.0e38f;
        float vm = a2;
        #pragma unroll
        for (int o = 8; o; o >>= 1) vm = fmaxf(vm, __shfl_xor(vm, o));
        float p2 = (lane < KNN) ? __expf(a2 - vm) : 0.f;
        float ss = p2;
        #pragma unroll
        for (int o = 8; o; o >>= 1) ss += __shfl_xor(ss, o);
        if (lane < KNN) s_p2[wid][lane] = p2;
        float aT = 0.f;
        if (lane < NH) {
            #pragma unroll
            for (int j2 = 0; j2 < KNN; ++j2)
                aT += s_p2[wid][j2] * s_te[s_nbi[wid][g][j2]][lane];
        }

        // phase 3: u-softmax, lane = u; (g,h) aggU
        float au = bat;
        #pragma unroll
        for (int h = 0; h < NH; ++h)
            au += ft(s_uk[lane][h] + s_tq[wid][h]) * wat[h];
        float um = au;
        #pragma unroll
        for (int o = 32; o; o >>= 1) um = fmaxf(um, __shfl_xor(um, o));
        float pu = __expf(au - um);
        float su = pu;
        #pragma unroll
        for (int o = 32; o; o >>= 1) su += __shfl_xor(su, o);
        s_pu[wid][lane] = pu;
        const int gb = (lane >> 3) << 3;
        const int hh = lane & 7;
        float aU = 0.f;
        #pragma unroll
        for (int i = 0; i < 8; ++i)
            aU += s_pu[wid][gb + i] * s_up[gb + i][hh];
        aU += __shfl_xor(aU, 8);
        aU += __shfl_xor(aU, 16);
        aU += __shfl_xor(aU, 32);

        // finalize on lanes 0-7 (h = lane)
        if (lane < NH) {
            float tqh = s_tq[wid][lane];
            float invT = 1.f / ss, invU = 1.f / su;
            float sig = 1.f / (1.f + __expf(-tqh));
            float x = sig * s_te[t][lane] + aT * invT + aU * invU;
            float r = x > 0.f ? x : __expf(x) - 1.f;
            out_task[(b * NT + t) * NH + lane] = r;
        }
    }
}

extern "C" void kernel_launch(void* const* d_in, const int* in_sizes, int n_in,
                              void* d_out, int out_size, void* d_ws, size_t ws_size,
                              hipStream_t stream)
{
    const float* usv_f  = (const float*)d_in[0];
    const float* task_f = (const float*)d_in[1];
    const int*   adj    = (const int*)  d_in[2];
    // d_in[3] edge_features: unused by the reference
    const float* W_usv  = (const float*)d_in[4];
    const float* b_usv  = (const float*)d_in[5];
    const float* W_task = (const float*)d_in[6];
    const float* b_task = (const float*)d_in[7];
    const float* W_au   = (const float*)d_in[8];
    const float* b_au   = (const float*)d_in[9];
    const float* W_at   = (const float*)d_in[10];
    const float* b_at   = (const float*)d_in[11];
    const float* W_Q    = (const float*)d_in[12];
    const float* b_Q    = (const float*)d_in[13];
    const float* W_K    = (const float*)d_in[14];
    const float* b_K    = (const float*)d_in[15];
    const float* W_V    = (const float*)d_in[16];
    const float* b_V    = (const float*)d_in[17];

    float* out_usv  = (float*)d_out;
    float* out_task = out_usv + NB * NU * NH;

    hipLaunchKernelGGL(k_usv2, dim3(NB * 8), dim3(512), 0, stream,
                       usv_f, task_f, adj,
                       W_usv, b_usv, W_task, b_task, W_au, b_au,
                       W_Q, b_Q, W_K, b_K, out_usv);
    hipLaunchKernelGGL(k_task6, dim3(NB * 8), dim3(512), 0, stream,
                       task_f, W_task, b_task, W_K, b_K, W_V, b_V,
                       W_Q, b_Q, W_at, b_at, out_usv, out_task);
}

// Round 15
// 78.914 us; speedup vs baseline: 1.3517x; 1.0631x over previous
//
#include <hip/hip_runtime.h>
#include <hip/hip_bf16.h>

#define NB 64
#define NU 64
#define NT 512
#define NH 8
#define KNN 9
#define PAD 9
#define UPB 8
#define NEGV -1000000000.0f

typedef unsigned long long ull;

// fast tanh via hardware exp: exact at saturation
__device__ __forceinline__ float ft(float x) {
    return 1.f - 2.f / (__expf(2.f * x) + 1.f);
}

// =====================================================================
// Kernel A (k_usv3): grid = NB*8 blocks, 512 threads = 8 waves.
// Wave wid owns u = (blk&7)*8 + wid. After one staging barrier the
// main loop is barrier-free: 2-pass wave softmax over 512 tasks
// (pass 1: scores in sc[8] regs + wave max; pass 2: exp + (g,h)
// wave-local LDS aggregation, verified r10/r12 mechanism).
// =====================================================================
__global__ void __launch_bounds__(512) k_usv3(
    const float* __restrict__ usv_f, const float* __restrict__ task_f,
    const int* __restrict__ adj,
    const float* __restrict__ W_usv, const float* __restrict__ b_usv,
    const float* __restrict__ W_task, const float* __restrict__ b_task,
    const float* __restrict__ W_au, const float* __restrict__ b_au,
    const float* __restrict__ W_Q, const float* __restrict__ b_Q,
    const float* __restrict__ W_K, const float* __restrict__ b_K,
    float* __restrict__ out_usv)
{
    __shared__ float s_te[NT][PAD];
    __shared__ float s_tk[NT][PAD];
    __shared__ float s_p[8][NU];

    const int b    = blockIdx.x >> 3;
    const int u0   = (blockIdx.x & 7) * UPB;
    const int tid  = threadIdx.x;
    const int lane = tid & 63, wid = tid >> 6;
    const int u    = u0 + wid;

    // --- staging: thread i -> te[i], tk[i] into LDS (verbatim r12) ---
    {
        int t = tid;
        float f[5];
        #pragma unroll
        for (int j = 0; j < 5; ++j) f[j] = task_f[(b * NT + t) * 5 + j];
        float e[NH];
        #pragma unroll
        for (int h = 0; h < NH; ++h) {
            float a = b_task[h];
            #pragma unroll
            for (int j = 0; j < 5; ++j) a += f[j] * W_task[j * NH + h];
            e[h] = a;
            s_te[t][h] = a;
        }
        #pragma unroll
        for (int h = 0; h < NH; ++h) {
            float a = b_K[h];
            #pragma unroll
            for (int j = 0; j < NH; ++j) a += e[j] * W_K[j * NH + h];
            s_tk[t][h] = a;
        }
    }

    // --- every lane: own-u usv_embed + q (redundant, r7-verified) ---
    float ue[NH], q[NH];
    {
        float f0 = usv_f[(b * NU + u) * 4 + 0];
        float f1 = usv_f[(b * NU + u) * 4 + 1];
        float f2 = usv_f[(b * NU + u) * 4 + 2];
        float f3 = usv_f[(b * NU + u) * 4 + 3];
        #pragma unroll
        for (int h = 0; h < NH; ++h)
            ue[h] = b_usv[h] + f0 * W_usv[0 * NH + h] + f1 * W_usv[1 * NH + h]
                             + f2 * W_usv[2 * NH + h] + f3 * W_usv[3 * NH + h];
        #pragma unroll
        for (int h = 0; h < NH; ++h) {
            float a = b_Q[h];
            #pragma unroll
            for (int j = 0; j < NH; ++j) a += ue[j] * W_Q[j * NH + h];
            q[h] = a;
        }
    }
    float wau[NH];
    #pragma unroll
    for (int h = 0; h < NH; ++h) wau[h] = W_au[h];
    const float bau = b_au[0];
    __syncthreads();

    const int* arow = adj + (b * NU + u) * NT;

    // --- pass 1: scores (regs) + wave max ---
    float sc[8];
    float m = -3.0e38f;
    #pragma unroll
    for (int i = 0; i < 8; ++i) {
        int t = i * 64 + lane;
        float a = bau;
        #pragma unroll
        for (int h = 0; h < NH; ++h) a += ft(q[h] + s_tk[t][h]) * wau[h];
        sc[i] = (arow[t] == 0) ? NEGV : a;
        m = fmaxf(m, sc[i]);
    }
    #pragma unroll
    for (int o = 32; o; o >>= 1) m = fmaxf(m, __shfl_xor(m, o));

    // --- pass 2: exp + sum + (g,h) aggregation (wave-local LDS) ---
    const int g8 = lane & ~7, hh = lane & 7;
    float ps = 0.f, part = 0.f;
    #pragma unroll
    for (int i = 0; i < 8; ++i) {
        float p = __expf(sc[i] - m);
        ps += p;
        s_p[wid][lane] = p;
        float acc = 0.f;
        #pragma unroll
        for (int k = 0; k < 8; ++k)
            acc += s_p[wid][g8 + k] * s_te[i * 64 + g8 + k][hh];
        part += acc;
    }
    #pragma unroll
    for (int o = 32; o; o >>= 1) ps += __shfl_xor(ps, o);
    part += __shfl_xor(part, 8);
    part += __shfl_xor(part, 16);
    part += __shfl_xor(part, 32);

    // --- finalize on lanes 0-7 (h = lane, static-index select) ---
    if (lane < NH) {
        float qh = q[0], ueh = ue[0];
        #pragma unroll
        for (int h = 1; h < NH; ++h)
            if (lane == h) { qh = q[h]; ueh = ue[h]; }
        float sig = 1.f / (1.f + __expf(-qh));
        float x = sig * ueh + part / ps;
        float upd = x > 0.f ? x : __expf(x) - 1.f;
        out_usv[(b * NU + u) * NH + lane] = upd;
    }
}

// =====================================================================
// Kernel B (k_task6): VERBATIM round-12 version (passed, 68.3us).
// =====================================================================
__global__ void __launch_bounds__(512) k_task6(
    const float* __restrict__ task_f,
    const float* __restrict__ W_task, const float* __restrict__ b_task,
    const float* __restrict__ W_K, const float* __restrict__ b_K,
    const float* __restrict__ W_V, const float* __restrict__ b_V,
    const float* __restrict__ W_Q, const float* __restrict__ b_Q,
    const float* __restrict__ W_at, const float* __restrict__ b_at,
    const float* __restrict__ out_usv,
    float* __restrict__ out_task)
{
    __shared__ float2 s_cxy[NT];
    __shared__ float s_te[NT][PAD];
    __shared__ float s_tk[NT][PAD];
    __shared__ float s_up[NU][PAD];
    __shared__ float s_uk[NU][PAD];
    __shared__ int   s_nbi[8][8][KNN];   // [wave][group][rank]
    __shared__ float s_p2[8][12];
    __shared__ float s_pu[8][NU];
    __shared__ float s_tq[8][PAD];

    const int b     = blockIdx.x >> 3;
    const int tile  = blockIdx.x & 7;
    const int wid   = threadIdx.x >> 6;
    const int lane  = threadIdx.x & 63;
    const int grp   = lane >> 3;          // group within wave
    const int lig   = lane & 7;           // lane in group
    const int tbase = tile * 64;
    const int myTask = tbase + wid * 8 + grp;   // kNN task of this lane

    // --- staging: thread i -> te/tk/coords of task i ---
    {
        int i = threadIdx.x;
        float f[5];
        #pragma unroll
        for (int j = 0; j < 5; ++j) f[j] = task_f[(b * NT + i) * 5 + j];
        s_cxy[i] = make_float2(f[0], f[1]);
        float e[NH];
        #pragma unroll
        for (int h = 0; h < NH; ++h) {
            float a = b_task[h];
            #pragma unroll
            for (int j = 0; j < 5; ++j) a += f[j] * W_task[j * NH + h];
            e[h] = a;
            s_te[i][h] = a;
        }
        #pragma unroll
        for (int h = 0; h < NH; ++h) {
            float a = b_K[h];
            #pragma unroll
            for (int j = 0; j < NH; ++j) a += e[j] * W_K[j * NH + h];
            s_tk[i][h] = a;
        }
    }
    if (threadIdx.x < NU) {
        int u = threadIdx.x;
        float up[NH];
        #pragma unroll
        for (int h = 0; h < NH; ++h) {
            up[h] = out_usv[(b * NU + u) * NH + h];
            s_up[u][h] = up[h];
        }
        #pragma unroll
        for (int h = 0; h < NH; ++h) {
            float a = b_Q[h];
            #pragma unroll
            for (int j = 0; j < NH; ++j) a += up[j] * W_Q[j * NH + h];
            s_uk[u][h] = a;
        }
    }
    __syncthreads();

    // --- kNN: per-lane sorted top-9 over candidates s = i*8+lig ---
    {
        float mx = s_cxy[myTask].x, my = s_cxy[myTask].y;
        ull a[KNN];
        #pragma unroll
        for (int j = 0; j < KNN; ++j) a[j] = ~0ULL;
        for (int i = 0; i < 64; ++i) {
            int s = i * 8 + lig;
            float2 c = s_cxy[s];
            float dx = mx - c.x, dy = my - c.y;
            float d = sqrtf(dx * dx + dy * dy);
            ull k = ((ull)__float_as_uint(d) << 32) | (unsigned)s;
            bool cnd[KNN];
            #pragma unroll
            for (int j = 0; j < KNN; ++j) cnd[j] = k < a[j];
            #pragma unroll
            for (int j = KNN - 1; j >= 1; --j)
                a[j] = cnd[j] ? (cnd[j - 1] ? a[j - 1] : k) : a[j];
            a[0] = cnd[0] ? k : a[0];
        }
        // merge within 8-lane group: 9 extraction rounds
        #pragma unroll
        for (int r = 0; r < KNN; ++r) {
            ull m = a[0];
            #pragma unroll
            for (int o = 1; o <= 4; o <<= 1) {
                ull m2 = __shfl_xor(m, o);
                m = (m2 < m) ? m2 : m;
            }
            if (lig == 0) s_nbi[wid][grp][r] = (int)(m & 511ULL);
            bool won = (a[0] == m);
            #pragma unroll
            for (int j = 0; j < KNN - 1; ++j) a[j] = won ? a[j + 1] : a[j];
            a[KNN - 1] = won ? ~0ULL : a[KNN - 1];
        }
    }

    float wat[NH];
    #pragma unroll
    for (int h = 0; h < NH; ++h) wat[h] = W_at[h];
    const float bat = b_at[0];

    // --- phases 2+3 (verified round-10 code), looped over 8 tasks ---
    for (int g = 0; g < 8; ++g) {
        const int t = tbase + wid * 8 + g;
        const int mynb = (lane < KNN) ? s_nbi[wid][g][lane] : t;

        // tq on lanes 0-7 -> s_tq (wave-local)
        if (lane < NH) {
            float a = b_V[lane];
            #pragma unroll
            for (int j = 0; j < NH; ++j) a += s_te[t][j] * W_V[j * NH + lane];
            s_tq[wid][lane] = a;
        }

        // phase 2: neighbor scoring (lanes 0-8 meaningful)
        float sc2 = bat;
        #pragma unroll
        for (int h = 0; h < NH; ++h)
            sc2 += ft(s_tq[wid][h] + s_tk[mynb][h]) * wat[h];
        float a2 = (lane < KNN) ? sc2 : -3.0e38f;
        float vm = a2;
        #pragma unroll
        for (int o = 8; o; o >>= 1) vm = fmaxf(vm, __shfl_xor(vm, o));
        float p2 = (lane < KNN) ? __expf(a2 - vm) : 0.f;
        float ss = p2;
        #pragma unroll
        for (int o = 8; o; o >>= 1) ss += __shfl_xor(ss, o);
        if (lane < KNN) s_p2[wid][lane] = p2;
        float aT = 0.f;
        if (lane < NH) {
            #pragma unroll
            for (int j2 = 0; j2 < KNN; ++j2)
                aT += s_p2[wid][j2] * s_te[s_nbi[wid][g][j2]][lane];
        }

        // phase 3: u-softmax, lane = u; (g,h) aggU
        float au = bat;
        #pragma unroll
        for (int h = 0; h < NH; ++h)
            au += ft(s_uk[lane][h] + s_tq[wid][h]) * wat[h];
        float um = au;
        #pragma unroll
        for (int o = 32; o; o >>= 1) um = fmaxf(um, __shfl_xor(um, o));
        float pu = __expf(au - um);
        float su = pu;
        #pragma unroll
        for (int o = 32; o; o >>= 1) su += __shfl_xor(su, o);
        s_pu[wid][lane] = pu;
        const int gb = (lane >> 3) << 3;
        const int hh = lane & 7;
        float aU = 0.f;
        #pragma unroll
        for (int i = 0; i < 8; ++i)
            aU += s_pu[wid][gb + i] * s_up[gb + i][hh];
        aU += __shfl_xor(aU, 8);
        aU += __shfl_xor(aU, 16);
        aU += __shfl_xor(aU, 32);

        // finalize on lanes 0-7 (h = lane)
        if (lane < NH) {
            float tqh = s_tq[wid][lane];
            float invT = 1.f / ss, invU = 1.f / su;
            float sig = 1.f / (1.f + __expf(-tqh));
            float x = sig * s_te[t][lane] + aT * invT + aU * invU;
            float r = x > 0.f ? x : __expf(x) - 1.f;
            out_task[(b * NT + t) * NH + lane] = r;
        }
    }
}

extern "C" void kernel_launch(void* const* d_in, const int* in_sizes, int n_in,
                              void* d_out, int out_size, void* d_ws, size_t ws_size,
                              hipStream_t stream)
{
    const float* usv_f  = (const float*)d_in[0];
    const float* task_f = (const float*)d_in[1];
    const int*   adj    = (const int*)  d_in[2];
    // d_in[3] edge_features: unused by the reference
    const float* W_usv  = (const float*)d_in[4];
    const float* b_usv  = (const float*)d_in[5];
    const float* W_task = (const float*)d_in[6];
    const float* b_task = (const float*)d_in[7];
    const float* W_au   = (const float*)d_in[8];
    const float* b_au   = (const float*)d_in[9];
    const float* W_at   = (const float*)d_in[10];
    const float* b_at   = (const float*)d_in[11];
    const float* W_Q    = (const float*)d_in[12];
    const float* b_Q    = (const float*)d_in[13];
    const float* W_K    = (const float*)d_in[14];
    const float* b_K    = (const float*)d_in[15];
    const float* W_V    = (const float*)d_in[16];
    const float* b_V    = (const float*)d_in[17];

    float* out_usv  = (float*)d_out;
    float* out_task = out_usv + NB * NU * NH;

    hipLaunchKernelGGL(k_usv3, dim3(NB * 8), dim3(512), 0, stream,
                       usv_f, task_f, adj,
                       W_usv, b_usv, W_task, b_task, W_au, b_au,
                       W_Q, b_Q, W_K, b_K, out_usv);
    hipLaunchKernelGGL(k_task6, dim3(NB * 8), dim3(512), 0, stream,
                       task_f, W_task, b_task, W_K, b_K, W_V, b_V,
                       W_Q, b_Q, W_at, b_at, out_usv, out_task);
}

// Round 16
// 78.689 us; speedup vs baseline: 1.3555x; 1.0029x over previous
//
#include <hip/hip_runtime.h>
#include <hip/hip_bf16.h>

#define NB 64
#define NU 64
#define NT 512
#define NH 8
#define KNN 9
#define PAD 9
#define UPB 8
#define NEGV -1000000000.0f

typedef unsigned long long ull;

// fast tanh via hardware exp: exact at saturation
__device__ __forceinline__ float ft(float x) {
    return 1.f - 2.f / (__expf(2.f * x) + 1.f);
}

// =====================================================================
// Kernel A (k_usv4): r15 k_usv3 + q/ue computed once on threads 0-7 and
// broadcast via LDS (r11-proven pattern). Barrier-free main loop.
// =====================================================================
__global__ void __launch_bounds__(512) k_usv4(
    const float* __restrict__ usv_f, const float* __restrict__ task_f,
    const int* __restrict__ adj,
    const float* __restrict__ W_usv, const float* __restrict__ b_usv,
    const float* __restrict__ W_task, const float* __restrict__ b_task,
    const float* __restrict__ W_au, const float* __restrict__ b_au,
    const float* __restrict__ W_Q, const float* __restrict__ b_Q,
    const float* __restrict__ W_K, const float* __restrict__ b_K,
    float* __restrict__ out_usv)
{
    __shared__ float s_te[NT][PAD];
    __shared__ float s_tk[NT][PAD];
    __shared__ float s_p[8][NU];
    __shared__ float s_q[UPB][PAD];
    __shared__ float s_ue[UPB][PAD];

    const int b    = blockIdx.x >> 3;
    const int u0   = (blockIdx.x & 7) * UPB;
    const int tid  = threadIdx.x;
    const int lane = tid & 63, wid = tid >> 6;
    const int u    = u0 + wid;

    // --- staging: thread i -> te[i], tk[i] into LDS (verbatim r12) ---
    {
        int t = tid;
        float f[5];
        #pragma unroll
        for (int j = 0; j < 5; ++j) f[j] = task_f[(b * NT + t) * 5 + j];
        float e[NH];
        #pragma unroll
        for (int h = 0; h < NH; ++h) {
            float a = b_task[h];
            #pragma unroll
            for (int j = 0; j < 5; ++j) a += f[j] * W_task[j * NH + h];
            e[h] = a;
            s_te[t][h] = a;
        }
        #pragma unroll
        for (int h = 0; h < NH; ++h) {
            float a = b_K[h];
            #pragma unroll
            for (int j = 0; j < NH; ++j) a += e[j] * W_K[j * NH + h];
            s_tk[t][h] = a;
        }
    }
    // --- u staging: threads 0..7 -> ue, q into LDS (r11-proven) ---
    if (tid < UPB) {
        int uu = u0 + tid;
        float f0 = usv_f[(b * NU + uu) * 4 + 0];
        float f1 = usv_f[(b * NU + uu) * 4 + 1];
        float f2 = usv_f[(b * NU + uu) * 4 + 2];
        float f3 = usv_f[(b * NU + uu) * 4 + 3];
        float ue[NH];
        #pragma unroll
        for (int h = 0; h < NH; ++h) {
            ue[h] = b_usv[h] + f0 * W_usv[0 * NH + h] + f1 * W_usv[1 * NH + h]
                             + f2 * W_usv[2 * NH + h] + f3 * W_usv[3 * NH + h];
            s_ue[tid][h] = ue[h];
        }
        #pragma unroll
        for (int h = 0; h < NH; ++h) {
            float a = b_Q[h];
            #pragma unroll
            for (int j = 0; j < NH; ++j) a += ue[j] * W_Q[j * NH + h];
            s_q[tid][h] = a;
        }
    }
    float wau[NH];
    #pragma unroll
    for (int h = 0; h < NH; ++h) wau[h] = W_au[h];
    const float bau = b_au[0];
    __syncthreads();

    // wave-uniform q from LDS -> registers (broadcast reads)
    float q[NH];
    #pragma unroll
    for (int h = 0; h < NH; ++h) q[h] = s_q[wid][h];

    const int* arow = adj + (b * NU + u) * NT;

    // --- pass 1: scores (regs) + wave max ---
    float sc[8];
    float m = -3.0e38f;
    #pragma unroll
    for (int i = 0; i < 8; ++i) {
        int t = i * 64 + lane;
        float a = bau;
        #pragma unroll
        for (int h = 0; h < NH; ++h) a += ft(q[h] + s_tk[t][h]) * wau[h];
        sc[i] = (arow[t] == 0) ? NEGV : a;
        m = fmaxf(m, sc[i]);
    }
    #pragma unroll
    for (int o = 32; o; o >>= 1) m = fmaxf(m, __shfl_xor(m, o));

    // --- pass 2: exp + sum + (g,h) aggregation (wave-local LDS) ---
    const int g8 = lane & ~7, hh = lane & 7;
    float ps = 0.f, part = 0.f;
    #pragma unroll
    for (int i = 0; i < 8; ++i) {
        float p = __expf(sc[i] - m);
        ps += p;
        s_p[wid][lane] = p;
        float acc = 0.f;
        #pragma unroll
        for (int k = 0; k < 8; ++k)
            acc += s_p[wid][g8 + k] * s_te[i * 64 + g8 + k][hh];
        part += acc;
    }
    #pragma unroll
    for (int o = 32; o; o >>= 1) ps += __shfl_xor(ps, o);
    part += __shfl_xor(part, 8);
    part += __shfl_xor(part, 16);
    part += __shfl_xor(part, 32);

    // --- finalize on lanes 0-7 (h = lane, direct LDS reads) ---
    if (lane < NH) {
        float qh  = s_q[wid][lane];
        float ueh = s_ue[wid][lane];
        float sig = 1.f / (1.f + __expf(-qh));
        float x = sig * ueh + part / ps;
        float upd = x > 0.f ? x : __expf(x) - 1.f;
        out_usv[(b * NU + u) * NH + lane] = upd;
    }
}

// =====================================================================
// Kernel B (k_task9): r12/r15 k_task6 with loop-invariant LDS reads
// (s_uk[lane][*], s_up[gb+i][hh]) hoisted to registers before the
// g-loop. All exchanges/machinery byte-identical to the passing r15.
// =====================================================================
__global__ void __launch_bounds__(512) k_task9(
    const float* __restrict__ task_f,
    const float* __restrict__ W_task, const float* __restrict__ b_task,
    const float* __restrict__ W_K, const float* __restrict__ b_K,
    const float* __restrict__ W_V, const float* __restrict__ b_V,
    const float* __restrict__ W_Q, const float* __restrict__ b_Q,
    const float* __restrict__ W_at, const float* __restrict__ b_at,
    const float* __restrict__ out_usv,
    float* __restrict__ out_task)
{
    __shared__ float2 s_cxy[NT];
    __shared__ float s_te[NT][PAD];
    __shared__ float s_tk[NT][PAD];
    __shared__ float s_up[NU][PAD];
    __shared__ float s_uk[NU][PAD];
    __shared__ int   s_nbi[8][8][KNN];   // [wave][group][rank]
    __shared__ float s_p2[8][12];
    __shared__ float s_pu[8][NU];
    __shared__ float s_tq[8][PAD];

    const int b     = blockIdx.x >> 3;
    const int tile  = blockIdx.x & 7;
    const int wid   = threadIdx.x >> 6;
    const int lane  = threadIdx.x & 63;
    const int grp   = lane >> 3;          // group within wave
    const int lig   = lane & 7;           // lane in group
    const int tbase = tile * 64;
    const int myTask = tbase + wid * 8 + grp;   // kNN task of this lane

    // --- staging: thread i -> te/tk/coords of task i ---
    {
        int i = threadIdx.x;
        float f[5];
        #pragma unroll
        for (int j = 0; j < 5; ++j) f[j] = task_f[(b * NT + i) * 5 + j];
        s_cxy[i] = make_float2(f[0], f[1]);
        float e[NH];
        #pragma unroll
        for (int h = 0; h < NH; ++h) {
            float a = b_task[h];
            #pragma unroll
            for (int j = 0; j < 5; ++j) a += f[j] * W_task[j * NH + h];
            e[h] = a;
            s_te[i][h] = a;
        }
        #pragma unroll
        for (int h = 0; h < NH; ++h) {
            float a = b_K[h];
            #pragma unroll
            for (int j = 0; j < NH; ++j) a += e[j] * W_K[j * NH + h];
            s_tk[i][h] = a;
        }
    }
    if (threadIdx.x < NU) {
        int u = threadIdx.x;
        float up[NH];
        #pragma unroll
        for (int h = 0; h < NH; ++h) {
            up[h] = out_usv[(b * NU + u) * NH + h];
            s_up[u][h] = up[h];
        }
        #pragma unroll
        for (int h = 0; h < NH; ++h) {
            float a = b_Q[h];
            #pragma unroll
            for (int j = 0; j < NH; ++j) a += up[j] * W_Q[j * NH + h];
            s_uk[u][h] = a;
        }
    }
    __syncthreads();

    // --- kNN: per-lane sorted top-9 over candidates s = i*8+lig ---
    {
        float mx = s_cxy[myTask].x, my = s_cxy[myTask].y;
        ull a[KNN];
        #pragma unroll
        for (int j = 0; j < KNN; ++j) a[j] = ~0ULL;
        for (int i = 0; i < 64; ++i) {
            int s = i * 8 + lig;
            float2 c = s_cxy[s];
            float dx = mx - c.x, dy = my - c.y;
            float d = sqrtf(dx * dx + dy * dy);
            ull k = ((ull)__float_as_uint(d) << 32) | (unsigned)s;
            bool cnd[KNN];
            #pragma unroll
            for (int j = 0; j < KNN; ++j) cnd[j] = k < a[j];
            #pragma unroll
            for (int j = KNN - 1; j >= 1; --j)
                a[j] = cnd[j] ? (cnd[j - 1] ? a[j - 1] : k) : a[j];
            a[0] = cnd[0] ? k : a[0];
        }
        // merge within 8-lane group: 9 extraction rounds
        #pragma unroll
        for (int r = 0; r < KNN; ++r) {
            ull m = a[0];
            #pragma unroll
            for (int o = 1; o <= 4; o <<= 1) {
                ull m2 = __shfl_xor(m, o);
                m = (m2 < m) ? m2 : m;
            }
            if (lig == 0) s_nbi[wid][grp][r] = (int)(m & 511ULL);
            bool won = (a[0] == m);
            #pragma unroll
            for (int j = 0; j < KNN - 1; ++j) a[j] = won ? a[j + 1] : a[j];
            a[KNN - 1] = won ? ~0ULL : a[KNN - 1];
        }
    }

    float wat[NH];
    #pragma unroll
    for (int h = 0; h < NH; ++h) wat[h] = W_at[h];
    const float bat = b_at[0];

    // --- hoist loop-invariant LDS reads to registers ---
    const int gb = (lane >> 3) << 3;
    const int hh = lane & 7;
    float uk_r[NH];
    #pragma unroll
    for (int h = 0; h < NH; ++h) uk_r[h] = s_uk[lane][h];
    float up_r[8];
    #pragma unroll
    for (int i = 0; i < 8; ++i) up_r[i] = s_up[gb + i][hh];

    // --- phases 2+3 (verified r12 machinery), looped over 8 tasks ---
    for (int g = 0; g < 8; ++g) {
        const int t = tbase + wid * 8 + g;
        const int mynb = (lane < KNN) ? s_nbi[wid][g][lane] : t;

        // tq on lanes 0-7 -> s_tq (wave-local)
        if (lane < NH) {
            float a = b_V[lane];
            #pragma unroll
            for (int j = 0; j < NH; ++j) a += s_te[t][j] * W_V[j * NH + lane];
            s_tq[wid][lane] = a;
        }

        // phase 2: neighbor scoring (lanes 0-8 meaningful)
        float sc2 = bat;
        #pragma unroll
        for (int h = 0; h < NH; ++h)
            sc2 += ft(s_tq[wid][h] + s_tk[mynb][h]) * wat[h];
        float a2 = (lane < KNN) ? sc2 : -3.0e38f;
        float vm = a2;
        #pragma unroll
        for (int o = 8; o; o >>= 1) vm = fmaxf(vm, __shfl_xor(vm, o));
        float p2 = (lane < KNN) ? __expf(a2 - vm) : 0.f;
        float ss = p2;
        #pragma unroll
        for (int o = 8; o; o >>= 1) ss += __shfl_xor(ss, o);
        if (lane < KNN) s_p2[wid][lane] = p2;
        float aT = 0.f;
        if (lane < NH) {
            #pragma unroll
            for (int j2 = 0; j2 < KNN; ++j2)
                aT += s_p2[wid][j2] * s_te[s_nbi[wid][g][j2]][lane];
        }

        // phase 3: u-softmax, lane = u; (g,h) aggU with hoisted regs
        float au = bat;
        #pragma unroll
        for (int h = 0; h < NH; ++h)
            au += ft(uk_r[h] + s_tq[wid][h]) * wat[h];
        float um = au;
        #pragma unroll
        for (int o = 32; o; o >>= 1) um = fmaxf(um, __shfl_xor(um, o));
        float pu = __expf(au - um);
        float su = pu;
        #pragma unroll
        for (int o = 32; o; o >>= 1) su += __shfl_xor(su, o);
        s_pu[wid][lane] = pu;
        float aU = 0.f;
        #pragma unroll
        for (int i = 0; i < 8; ++i)
            aU += s_pu[wid][gb + i] * up_r[i];
        aU += __shfl_xor(aU, 8);
        aU += __shfl_xor(aU, 16);
        aU += __shfl_xor(aU, 32);

        // finalize on lanes 0-7 (h = lane)
        if (lane < NH) {
            float tqh = s_tq[wid][lane];
            float invT = 1.f / ss, invU = 1.f / su;
            float sig = 1.f / (1.f + __expf(-tqh));
            float x = sig * s_te[t][lane] + aT * invT + aU * invU;
            float r = x > 0.f ? x : __expf(x) - 1.f;
            out_task[(b * NT + t) * NH + lane] = r;
        }
    }
}

extern "C" void kernel_launch(void* const* d_in, const int* in_sizes, int n_in,
                              void* d_out, int out_size, void* d_ws, size_t ws_size,
                              hipStream_t stream)
{
    const float* usv_f  = (const float*)d_in[0];
    const float* task_f = (const float*)d_in[1];
    const int*   adj    = (const int*)  d_in[2];
    // d_in[3] edge_features: unused by the reference
    const float* W_usv  = (const float*)d_in[4];
    const float* b_usv  = (const float*)d_in[5];
    const float* W_task = (const float*)d_in[6];
    const float* b_task = (const float*)d_in[7];
    const float* W_au   = (const float*)d_in[8];
    const float* b_au   = (const float*)d_in[9];
    const float* W_at   = (const float*)d_in[10];
    const float* b_at   = (const float*)d_in[11];
    const float* W_Q    = (const float*)d_in[12];
    const float* b_Q    = (const float*)d_in[13];
    const float* W_K    = (const float*)d_in[14];
    const float* b_K    = (const float*)d_in[15];
    const float* W_V    = (const float*)d_in[16];
    const float* b_V    = (const float*)d_in[17];

    float* out_usv  = (float*)d_out;
    float* out_task = out_usv + NB * NU * NH;

    hipLaunchKernelGGL(k_usv4, dim3(NB * 8), dim3(512), 0, stream,
                       usv_f, task_f, adj,
                       W_usv, b_usv, W_task, b_task, W_au, b_au,
                       W_Q, b_Q, W_K, b_K, out_usv);
    hipLaunchKernelGGL(k_task9, dim3(NB * 8), dim3(512), 0, stream,
                       task_f, W_task, b_task, W_K, b_K, W_V, b_V,
                       W_Q, b_Q, W_at, b_at, out_usv, out_task);
}

// Round 18
// 73.936 us; speedup vs baseline: 1.4427x; 1.0643x over previous
//
#include <hip/hip_runtime.h>
#include <hip/hip_bf16.h>

#define NB 64
#define NU 64
#define NT 512
#define NH 8
#define KNN 9
#define PAD 9
#define UPB 8
#define NEGV -1000000000.0f

typedef unsigned long long ull;

// fast tanh via hardware exp: exact at saturation
__device__ __forceinline__ float ft(float x) {
    return 1.f - 2.f / (__expf(2.f * x) + 1.f);
}

// =====================================================================
// Kernel A (k_usv4): verbatim round 16 (passing, ~10us).
// =====================================================================
__global__ void __launch_bounds__(512) k_usv4(
    const float* __restrict__ usv_f, const float* __restrict__ task_f,
    const int* __restrict__ adj,
    const float* __restrict__ W_usv, const float* __restrict__ b_usv,
    const float* __restrict__ W_task, const float* __restrict__ b_task,
    const float* __restrict__ W_au, const float* __restrict__ b_au,
    const float* __restrict__ W_Q, const float* __restrict__ b_Q,
    const float* __restrict__ W_K, const float* __restrict__ b_K,
    float* __restrict__ out_usv)
{
    __shared__ float s_te[NT][PAD];
    __shared__ float s_tk[NT][PAD];
    __shared__ float s_p[8][NU];
    __shared__ float s_q[UPB][PAD];
    __shared__ float s_ue[UPB][PAD];

    const int b    = blockIdx.x >> 3;
    const int u0   = (blockIdx.x & 7) * UPB;
    const int tid  = threadIdx.x;
    const int lane = tid & 63, wid = tid >> 6;
    const int u    = u0 + wid;

    {
        int t = tid;
        float f[5];
        #pragma unroll
        for (int j = 0; j < 5; ++j) f[j] = task_f[(b * NT + t) * 5 + j];
        float e[NH];
        #pragma unroll
        for (int h = 0; h < NH; ++h) {
            float a = b_task[h];
            #pragma unroll
            for (int j = 0; j < 5; ++j) a += f[j] * W_task[j * NH + h];
            e[h] = a;
            s_te[t][h] = a;
        }
        #pragma unroll
        for (int h = 0; h < NH; ++h) {
            float a = b_K[h];
            #pragma unroll
            for (int j = 0; j < NH; ++j) a += e[j] * W_K[j * NH + h];
            s_tk[t][h] = a;
        }
    }
    if (tid < UPB) {
        int uu = u0 + tid;
        float f0 = usv_f[(b * NU + uu) * 4 + 0];
        float f1 = usv_f[(b * NU + uu) * 4 + 1];
        float f2 = usv_f[(b * NU + uu) * 4 + 2];
        float f3 = usv_f[(b * NU + uu) * 4 + 3];
        float ue[NH];
        #pragma unroll
        for (int h = 0; h < NH; ++h) {
            ue[h] = b_usv[h] + f0 * W_usv[0 * NH + h] + f1 * W_usv[1 * NH + h]
                             + f2 * W_usv[2 * NH + h] + f3 * W_usv[3 * NH + h];
            s_ue[tid][h] = ue[h];
        }
        #pragma unroll
        for (int h = 0; h < NH; ++h) {
            float a = b_Q[h];
            #pragma unroll
            for (int j = 0; j < NH; ++j) a += ue[j] * W_Q[j * NH + h];
            s_q[tid][h] = a;
        }
    }
    float wau[NH];
    #pragma unroll
    for (int h = 0; h < NH; ++h) wau[h] = W_au[h];
    const float bau = b_au[0];
    __syncthreads();

    float q[NH];
    #pragma unroll
    for (int h = 0; h < NH; ++h) q[h] = s_q[wid][h];

    const int* arow = adj + (b * NU + u) * NT;

    float sc[8];
    float m = -3.0e38f;
    #pragma unroll
    for (int i = 0; i < 8; ++i) {
        int t = i * 64 + lane;
        float a = bau;
        #pragma unroll
        for (int h = 0; h < NH; ++h) a += ft(q[h] + s_tk[t][h]) * wau[h];
        sc[i] = (arow[t] == 0) ? NEGV : a;
        m = fmaxf(m, sc[i]);
    }
    #pragma unroll
    for (int o = 32; o; o >>= 1) m = fmaxf(m, __shfl_xor(m, o));

    const int g8 = lane & ~7, hh = lane & 7;
    float ps = 0.f, part = 0.f;
    #pragma unroll
    for (int i = 0; i < 8; ++i) {
        float p = __expf(sc[i] - m);
        ps += p;
        s_p[wid][lane] = p;
        float acc = 0.f;
        #pragma unroll
        for (int k = 0; k < 8; ++k)
            acc += s_p[wid][g8 + k] * s_te[i * 64 + g8 + k][hh];
        part += acc;
    }
    #pragma unroll
    for (int o = 32; o; o >>= 1) ps += __shfl_xor(ps, o);
    part += __shfl_xor(part, 8);
    part += __shfl_xor(part, 16);
    part += __shfl_xor(part, 32);

    if (lane < NH) {
        float qh  = s_q[wid][lane];
        float ueh = s_ue[wid][lane];
        float sig = 1.f / (1.f + __expf(-qh));
        float x = sig * ueh + part / ps;
        float upd = x > 0.f ? x : __expf(x) - 1.f;
        out_usv[(b * NU + u) * NH + lane] = upd;
    }
}

// =====================================================================
// Kernel B (k_task10): round-16 k_task9 verbatim EXCEPT kNN distance is
// squared (d2, no sqrtf) — r9-proven equivalent on this dataset (same
// u64 lex key, same tie semantics; sqrt is monotonic and r9 passed with
// d2+idx ties, absmax bit-identical).
// =====================================================================
__global__ void __launch_bounds__(512) k_task10(
    const float* __restrict__ task_f,
    const float* __restrict__ W_task, const float* __restrict__ b_task,
    const float* __restrict__ W_K, const float* __restrict__ b_K,
    const float* __restrict__ W_V, const float* __restrict__ b_V,
    const float* __restrict__ W_Q, const float* __restrict__ b_Q,
    const float* __restrict__ W_at, const float* __restrict__ b_at,
    const float* __restrict__ out_usv,
    float* __restrict__ out_task)
{
    __shared__ float2 s_cxy[NT];
    __shared__ float s_te[NT][PAD];
    __shared__ float s_tk[NT][PAD];
    __shared__ float s_up[NU][PAD];
    __shared__ float s_uk[NU][PAD];
    __shared__ int   s_nbi[8][8][KNN];   // [wave][group][rank]
    __shared__ float s_p2[8][12];
    __shared__ float s_pu[8][NU];
    __shared__ float s_tq[8][PAD];

    const int b     = blockIdx.x >> 3;
    const int tile  = blockIdx.x & 7;
    const int wid   = threadIdx.x >> 6;
    const int lane  = threadIdx.x & 63;
    const int grp   = lane >> 3;          // group within wave
    const int lig   = lane & 7;           // lane in group
    const int tbase = tile * 64;
    const int myTask = tbase + wid * 8 + grp;   // kNN task of this lane

    // --- staging: thread i -> te/tk/coords of task i ---
    {
        int i = threadIdx.x;
        float f[5];
        #pragma unroll
        for (int j = 0; j < 5; ++j) f[j] = task_f[(b * NT + i) * 5 + j];
        s_cxy[i] = make_float2(f[0], f[1]);
        float e[NH];
        #pragma unroll
        for (int h = 0; h < NH; ++h) {
            float a = b_task[h];
            #pragma unroll
            for (int j = 0; j < 5; ++j) a += f[j] * W_task[j * NH + h];
            e[h] = a;
            s_te[i][h] = a;
        }
        #pragma unroll
        for (int h = 0; h < NH; ++h) {
            float a = b_K[h];
            #pragma unroll
            for (int j = 0; j < NH; ++j) a += e[j] * W_K[j * NH + h];
            s_tk[i][h] = a;
        }
    }
    if (threadIdx.x < NU) {
        int u = threadIdx.x;
        float up[NH];
        #pragma unroll
        for (int h = 0; h < NH; ++h) {
            up[h] = out_usv[(b * NU + u) * NH + h];
            s_up[u][h] = up[h];
        }
        #pragma unroll
        for (int h = 0; h < NH; ++h) {
            float a = b_Q[h];
            #pragma unroll
            for (int j = 0; j < NH; ++j) a += up[j] * W_Q[j * NH + h];
            s_uk[u][h] = a;
        }
    }
    __syncthreads();

    // --- kNN: per-lane sorted top-9 over candidates s = i*8+lig ---
    {
        float mx = s_cxy[myTask].x, my = s_cxy[myTask].y;
        ull a[KNN];
        #pragma unroll
        for (int j = 0; j < KNN; ++j) a[j] = ~0ULL;
        for (int i = 0; i < 64; ++i) {
            int s = i * 8 + lig;
            float2 c = s_cxy[s];
            float dx = mx - c.x, dy = my - c.y;
            float d = dx * dx + dy * dy;          // squared dist (r9-proven)
            ull k = ((ull)__float_as_uint(d) << 32) | (unsigned)s;
            bool cnd[KNN];
            #pragma unroll
            for (int j = 0; j < KNN; ++j) cnd[j] = k < a[j];
            #pragma unroll
            for (int j = KNN - 1; j >= 1; --j)
                a[j] = cnd[j] ? (cnd[j - 1] ? a[j - 1] : k) : a[j];
            a[0] = cnd[0] ? k : a[0];
        }
        // merge within 8-lane group: 9 extraction rounds
        #pragma unroll
        for (int r = 0; r < KNN; ++r) {
            ull m = a[0];
            #pragma unroll
            for (int o = 1; o <= 4; o <<= 1) {
                ull m2 = __shfl_xor(m, o);
                m = (m2 < m) ? m2 : m;
            }
            if (lig == 0) s_nbi[wid][grp][r] = (int)(m & 511ULL);
            bool won = (a[0] == m);
            #pragma unroll
            for (int j = 0; j < KNN - 1; ++j) a[j] = won ? a[j + 1] : a[j];
            a[KNN - 1] = won ? ~0ULL : a[KNN - 1];
        }
    }

    float wat[NH];
    #pragma unroll
    for (int h = 0; h < NH; ++h) wat[h] = W_at[h];
    const float bat = b_at[0];

    // --- hoist loop-invariant LDS reads to registers ---
    const int gb = (lane >> 3) << 3;
    const int hh = lane & 7;
    float uk_r[NH];
    #pragma unroll
    for (int h = 0; h < NH; ++h) uk_r[h] = s_uk[lane][h];
    float up_r[8];
    #pragma unroll
    for (int i = 0; i < 8; ++i) up_r[i] = s_up[gb + i][hh];

    // --- phases 2+3 (verified r12/r16 machinery), looped over 8 tasks ---
    for (int g = 0; g < 8; ++g) {
        const int t = tbase + wid * 8 + g;
        const int mynb = (lane < KNN) ? s_nbi[wid][g][lane] : t;

        // tq on lanes 0-7 -> s_tq (wave-local)
        if (lane < NH) {
            float a = b_V[lane];
            #pragma unroll
            for (int j = 0; j < NH; ++j) a += s_te[t][j] * W_V[j * NH + lane];
            s_tq[wid][lane] = a;
        }

        // phase 2: neighbor scoring (lanes 0-8 meaningful)
        float sc2 = bat;
        #pragma unroll
        for (int h = 0; h < NH; ++h)
            sc2 += ft(s_tq[wid][h] + s_tk[mynb][h]) * wat[h];
        float a2 = (lane < KNN) ? sc2 : -3.0e38f;
        float vm = a2;
        #pragma unroll
        for (int o = 8; o; o >>= 1) vm = fmaxf(vm, __shfl_xor(vm, o));
        float p2 = (lane < KNN) ? __expf(a2 - vm) : 0.f;
        float ss = p2;
        #pragma unroll
        for (int o = 8; o; o >>= 1) ss += __shfl_xor(ss, o);
        if (lane < KNN) s_p2[wid][lane] = p2;
        float aT = 0.f;
        if (lane < NH) {
            #pragma unroll
            for (int j2 = 0; j2 < KNN; ++j2)
                aT += s_p2[wid][j2] * s_te[s_nbi[wid][g][j2]][lane];
        }

        // phase 3: u-softmax, lane = u; (g,h) aggU with hoisted regs
        float au = bat;
        #pragma unroll
        for (int h = 0; h < NH; ++h)
            au += ft(uk_r[h] + s_tq[wid][h]) * wat[h];
        float um = au;
        #pragma unroll
        for (int o = 32; o; o >>= 1) um = fmaxf(um, __shfl_xor(um, o));
        float pu = __expf(au - um);
        float su = pu;
        #pragma unroll
        for (int o = 32; o; o >>= 1) su += __shfl_xor(su, o);
        s_pu[wid][lane] = pu;
        float aU = 0.f;
        #pragma unroll
        for (int i = 0; i < 8; ++i)
            aU += s_pu[wid][gb + i] * up_r[i];
        aU += __shfl_xor(aU, 8);
        aU += __shfl_xor(aU, 16);
        aU += __shfl_xor(aU, 32);

        // finalize on lanes 0-7 (h = lane)
        if (lane < NH) {
            float tqh = s_tq[wid][lane];
            float invT = 1.f / ss, invU = 1.f / su;
            float sig = 1.f / (1.f + __expf(-tqh));
            float x = sig * s_te[t][lane] + aT * invT + aU * invU;
            float r = x > 0.f ? x : __expf(x) - 1.f;
            out_task[(b * NT + t) * NH + lane] = r;
        }
    }
}

extern "C" void kernel_launch(void* const* d_in, const int* in_sizes, int n_in,
                              void* d_out, int out_size, void* d_ws, size_t ws_size,
                              hipStream_t stream)
{
    const float* usv_f  = (const float*)d_in[0];
    const float* task_f = (const float*)d_in[1];
    const int*   adj    = (const int*)  d_in[2];
    // d_in[3] edge_features: unused by the reference
    const float* W_usv  = (const float*)d_in[4];
    const float* b_usv  = (const float*)d_in[5];
    const float* W_task = (const float*)d_in[6];
    const float* b_task = (const float*)d_in[7];
    const float* W_au   = (const float*)d_in[8];
    const float* b_au   = (const float*)d_in[9];
    const float* W_at   = (const float*)d_in[10];
    const float* b_at   = (const float*)d_in[11];
    const float* W_Q    = (const float*)d_in[12];
    const float* b_Q    = (const float*)d_in[13];
    const float* W_K    = (const float*)d_in[14];
    const float* b_K    = (const float*)d_in[15];
    const float* W_V    = (const float*)d_in[16];
    const float* b_V    = (const float*)d_in[17];

    float* out_usv  = (float*)d_out;
    float* out_task = out_usv + NB * NU * NH;

    hipLaunchKernelGGL(k_usv4, dim3(NB * 8), dim3(512), 0, stream,
                       usv_f, task_f, adj,
                       W_usv, b_usv, W_task, b_task, W_au, b_au,
                       W_Q, b_Q, W_K, b_K, out_usv);
    hipLaunchKernelGGL(k_task10, dim3(NB * 8), dim3(512), 0, stream,
                       task_f, W_task, b_task, W_K, b_K, W_V, b_V,
                       W_Q, b_Q, W_at, b_at, out_usv, out_task);
}